// Round 1
// baseline (452.667 us; speedup 1.0000x reference)
//
#include <hip/hip_runtime.h>
#include <hip/hip_bf16.h>

// DeepseekV3 MoE: B=2,S=2048 -> n=4096 tokens, H=1024, I=256, E=256, K=8, G=8, TG=4, NS=2
// All inputs f32. Output f32 [4096][1024].

typedef __attribute__((ext_vector_type(4))) float  f32x4;
typedef __attribute__((ext_vector_type(8))) short  bf16x8;
typedef __attribute__((ext_vector_type(4))) short  bf16x4;
typedef __attribute__((ext_vector_type(4))) unsigned short u16x4;

#define DI static __device__ __forceinline__

DI unsigned short f2bf(float f){
  unsigned u = __builtin_bit_cast(unsigned, f);
  return (unsigned short)((u + 0x7FFFu + ((u>>16)&1u)) >> 16); // RNE (inputs finite)
}
DI float bf2f(unsigned short s){
  return __builtin_bit_cast(float, ((unsigned)s)<<16);
}

// ---------------- workspace layout (bytes) ----------------
#define WS_XBF      0u          /* 4096*1024 bf16 = 8,388,608 */
#define WS_HSH      8388608u    /* 4096*512 bf16  = 4,194,304 (shared h, concat s) */
#define WS_HMID     12582912u   /* 32768*256 bf16 = 16,777,216 */
#define WS_YSLOT    29360128u   /* 32768*1024 bf16= 67,108,864 */
#define WS_TOPKI    96468992u   /* 4096*8 int */
#define WS_TOPKW    96600064u   /* 4096*8 f32 */
#define WS_TOKMAP   96731136u   /* 32768 int */
#define WS_SLOTMAP  96862208u   /* 32768 int */
#define WS_CNT      96993280u   /* 256 int */
#define WS_CURSOR   96994304u   /* 256 int */
#define WS_ZERO     96995328u   /* 4096 B zeros (covers k0*2 + lane offs) */
#define WS_OFF      96999424u   /* 257 int */

// ---------------- convert x -> bf16 ----------------
__global__ void k_convert(const float* __restrict__ x, unsigned short* __restrict__ xbf){
  size_t i = ((size_t)blockIdx.x*256 + threadIdx.x)*8;
  f32x4 v0 = *(const f32x4*)(x+i), v1 = *(const f32x4*)(x+i+4);
  u16x4 a, b;
  a[0]=f2bf(v0[0]); a[1]=f2bf(v0[1]); a[2]=f2bf(v0[2]); a[3]=f2bf(v0[3]);
  b[0]=f2bf(v1[0]); b[1]=f2bf(v1[1]); b[2]=f2bf(v1[2]); b[3]=f2bf(v1[3]);
  *(u16x4*)(xbf+i) = a; *(u16x4*)(xbf+i+4) = b;
}

// ---------------- router: logits (f32, f64-combined) + grouped top-k + softmax ----------------
__global__ __launch_bounds__(256) void k_router(const float* __restrict__ x, const float* __restrict__ Wg,
                                                int* __restrict__ topki, float* __restrict__ topkw,
                                                int* __restrict__ cnt){
  __shared__ float xs[8][1024];   // 32KB
  __shared__ float lg[8][256];    // 8KB
  __shared__ float cv[8][32];
  __shared__ int   ce[8][32];
  const int tid = threadIdx.x;
  const int t0  = blockIdx.x * 8;
  {
    const f32x4* xg = (const f32x4*)(x + (size_t)t0*1024);
    f32x4* xs4 = (f32x4*)&xs[0][0];
    #pragma unroll
    for (int i=0;i<8;++i) xs4[tid + i*256] = xg[tid + i*256];
  }
  __syncthreads();
  { // expert e = tid; 8 tokens; LDS reads are wave-uniform -> broadcast
    const f32x4* wg4 = (const f32x4*)(Wg + (size_t)tid*1024);
    f32x4 a[8];
    #pragma unroll
    for (int t=0;t<8;++t) a[t] = (f32x4){0.f,0.f,0.f,0.f};
    for (int i=0;i<256;++i){
      f32x4 w = wg4[i];
      #pragma unroll
      for (int t=0;t<8;++t) a[t] += w * ((const f32x4*)&xs[t][0])[i];
    }
    #pragma unroll
    for (int t=0;t<8;++t){
      double d = ((double)a[t][0] + (double)a[t][1]) + ((double)a[t][2] + (double)a[t][3]);
      lg[t][tid] = (float)d;
    }
  }
  __syncthreads();
  if (tid < 64){ // per (token, group): top-4 of 32, ties -> lowest index
    int tok = tid>>3, grp = tid&7;
    unsigned mask = 0;
    for (int j=0;j<4;++j){
      float best = -3.4e38f; int bi = 0;
      for (int i=0;i<32;++i){
        float v = lg[tok][grp*32+i];
        if (!((mask>>i)&1u) && v > best){ best=v; bi=i; }
      }
      mask |= 1u<<bi;
      cv[tok][grp*4+j] = best; ce[tok][grp*4+j] = grp*32+bi;
    }
  }
  __syncthreads();
  if (tid < 8){ // per token: top-8 of 32 candidates (pos order = group-major desc) + softmax
    int tok = tid; unsigned mask=0;
    float vals[8]; int es[8];
    #pragma unroll
    for (int k=0;k<8;++k){
      float best=-3.4e38f; int bp=0;
      for (int p=0;p<32;++p){
        float v = cv[tok][p];
        if (!((mask>>p)&1u) && v > best){ best=v; bp=p; }
      }
      mask|=1u<<bp; vals[k]=best; es[k]=ce[tok][bp];
    }
    float m = vals[0], s=0.f, w[8];
    #pragma unroll
    for (int k=0;k<8;++k){ w[k]=expf(vals[k]-m); s+=w[k]; }
    float inv = 1.f/s;
    #pragma unroll
    for (int k=0;k<8;++k){
      int g=(t0+tok)*8+k;
      topki[g]=es[k]; topkw[g]=w[k]*inv;
      atomicAdd(&cnt[es[k]],1);
    }
  }
}

// ---------------- exclusive scan of 256 counts ----------------
__global__ void k_scan(const int* __restrict__ cnt, int* __restrict__ off){
  __shared__ int s[256];
  int tid=threadIdx.x;
  s[tid]=cnt[tid]; __syncthreads();
  for (int d=1; d<256; d<<=1){
    int v = (tid>=d)? s[tid-d] : 0; __syncthreads();
    s[tid]+=v; __syncthreads();
  }
  off[tid+1]=s[tid]; if(tid==0) off[0]=0;
}

// ---------------- scatter tokens into per-expert slots ----------------
__global__ void k_scatter(const int* __restrict__ topki, const int* __restrict__ off,
                          int* __restrict__ cursor, int* __restrict__ tokmap, int* __restrict__ slotmap){
  int g = blockIdx.x*256 + threadIdx.x;
  int e = topki[g];
  int p = off[e] + atomicAdd(&cursor[e], 1);
  tokmap[p] = g >> 3;
  slotmap[g] = p;
}

// ---------------- ragged MFMA GEMM (BM=256, BN=256, BK=32, 8 waves) ----------------
// GEMM==1: gate_up.  e<256: routed (A=xbf gathered, B=W_gate_up[e], out=hmid silu-gated bf16)
//          e>=256:   shared s=e-256 (A=xbf dense, B=Ws_gate_up[s], out=hsh cols s*256+..)
//          nc in {0,1}: covers g cols [nc*128,+128) paired with u cols [256+nc*128,+128).
// GEMM==2: down.     e<256: routed (A=hmid rows, B=W_down[e], out=yslot bf16)
//          e==256:   shared (A=hsh K=512, B=Ws_down flat [512][1024], out=d_out f32 * 0.5)
template<int GEMM>
__global__ __launch_bounds__(512, 2) void k_gemm(
    const unsigned short* __restrict__ A1, const unsigned short* __restrict__ A2,
    const float* __restrict__ WE, const float* __restrict__ WS,
    const int* __restrict__ cnt, const int* __restrict__ off,
    const int* __restrict__ tokmap,
    unsigned short* __restrict__ O1, unsigned short* __restrict__ O2,
    float* __restrict__ OD, const unsigned short* __restrict__ zpage)
{
  __shared__ __align__(16) char smem[65536]; // As[2][256][32]bf16 (32KB) | Bs[2] rot-subtiled (32KB); reused as Hs[256][128]
  const int e = blockIdx.x, mt = blockIdx.y, nc = blockIdx.z;
  const bool sh = (e >= 256);
  const int M = sh ? 4096 : cnt[e];
  const int Moff = mt*256;
  if (Moff >= M) return;
  const int tid=threadIdx.x, ln=tid&63, wv=tid>>6, wm=wv>>2, wn=wv&3, lrow=ln&15, lk=ln>>4;
  const int Ktot = (GEMM==1)?1024:(sh?512:256);
  const int ldB  = (GEMM==1)?512:1024;
  const float* B = (GEMM==1) ? (sh? WS + (size_t)(e-256)*524288 : WE + (size_t)e*524288)
                             : (sh? WS : WE + (size_t)e*262144);
  const int offe = sh? 0 : off[e];

  // per-thread A staging sources (2 gload issues per wave per K-step), 16B/lane
  const char* a_src[2];
  #pragma unroll
  for (int qi=0;qi<2;++qi){
    int row  = (wv*2+qi)*16 + (ln>>2);
    int grow = Moff + row;
    const unsigned short* p;
    if (GEMM==1){
      if (!sh) p = (grow < M)? A1 + (size_t)tokmap[offe+grow]*1024 : zpage;
      else     p = A1 + (size_t)grow*1024;
    } else {
      if (!sh) p = (grow < M)? A1 + ((size_t)offe+grow)*256 : zpage;
      else     p = A2 + (size_t)grow*512;
    }
    a_src[qi] = (const char*)p + (ln&3)*16;
  }
  const int cl = ln*4;                                  // local B col base (0..252)
  const int gc = (GEMM==1)? (nc*128 + cl + ((cl>=128)?128:0)) : (nc*256 + cl);
  float br[16];
  f32x4 acc[8][4] = {};

  auto stageA = [&](int buf, int k0){
    #pragma unroll
    for (int qi=0;qi<2;++qi)
      __builtin_amdgcn_global_load_lds((const void*)(a_src[qi] + (size_t)k0*2),
          (void*)(smem + buf*16384 + (wv*2+qi)*1024), 16, 0, 0);
  };
  auto loadB = [&](int k0){
    #pragma unroll
    for (int r=0;r<4;++r){
      f32x4 v = *(const f32x4*)(B + (size_t)(k0 + 4*wv + r)*ldB + gc);
      br[r*4+0]=v[0]; br[r*4+1]=v[1]; br[r*4+2]=v[2]; br[r*4+3]=v[3];
    }
  };
  auto writeB = [&](int buf){ // rotated-subtile: tile(nt,kt)=(n>>4,k>>2) at ((nt*8+kt)*64), slot p=((n&15)+nt+kt)&15
    #pragma unroll
    for (int i=0;i<4;++i){
      int c = cl + i, nt = c>>4, p = ((c&15) + nt + wv) & 15;
      unsigned short* d = (unsigned short*)(smem + 32768 + buf*16384) + ((nt*8+wv)*64 + p*4);
      u16x4 pk; pk[0]=f2bf(br[0*4+i]); pk[1]=f2bf(br[1*4+i]); pk[2]=f2bf(br[2*4+i]); pk[3]=f2bf(br[3*4+i]);
      *(u16x4*)d = pk;
    }
  };
  auto compute = [&](int buf){
    const short* as = (const short*)(smem + buf*16384);
    const short* bs = (const short*)(smem + 32768 + buf*16384);
    bf16x8 af[8]; bf16x8 bfr[4];
    #pragma unroll
    for (int mi=0;mi<8;++mi) af[mi] = *(const bf16x8*)(as + (wm*128+mi*16+lrow)*32 + lk*8);
    #pragma unroll
    for (int ni=0;ni<4;++ni){
      int n0 = (GEMM==1)? ((ni<2)? wn*32+ni*16 : 128+wn*32+(ni-2)*16) : (wn*64+ni*16);
      int nt = n0>>4, kt = lk*2;
      int p0=((lrow+nt+kt)&15), p1=((lrow+nt+kt+1)&15);
      bf16x4 lo = *(const bf16x4*)(bs + (nt*8+kt  )*64 + p0*4);
      bf16x4 hi = *(const bf16x4*)(bs + (nt*8+kt+1)*64 + p1*4);
      bfr[ni] = __builtin_shufflevector(lo, hi, 0,1,2,3,4,5,6,7);
    }
    #pragma unroll
    for (int mi=0;mi<8;++mi)
      #pragma unroll
      for (int ni=0;ni<4;++ni)
        acc[mi][ni] = __builtin_amdgcn_mfma_f32_16x16x32_bf16(af[mi], bfr[ni], acc[mi][ni], 0,0,0);
  };

  stageA(0,0); loadB(0);
  const int nsteps = Ktot>>5;
  for (int t=0;t<nsteps;++t){
    int b=t&1;
    asm volatile("s_waitcnt vmcnt(0)" ::: "memory"); // drain gload_lds (As[b]) + br regs
    writeB(b);
    __syncthreads();                                 // As[b]/Bs[b] visible block-wide
    if (t+1<nsteps){ stageA(b^1,(t+1)<<5); loadB((t+1)<<5); } // prefetch under MFMA
    compute(b);
  }

  if (GEMM==1){ // silu(g)*u epilogue via LDS repack (Hs aliases smem)
    __syncthreads();
    unsigned short* Hs = (unsigned short*)smem; // [256][128]
    #pragma unroll
    for (int mi=0;mi<8;++mi)
      #pragma unroll
      for (int ni=0;ni<2;++ni){
        f32x4 g = acc[mi][ni], u = acc[mi][ni+2];
        #pragma unroll
        for (int r=0;r<4;++r){
          float gg = g[r];
          float hh = (gg / (1.f + __expf(-gg))) * u[r];
          int m = wm*128 + mi*16 + lk*4 + r;
          int c = wn*32 + ni*16 + lrow;
          Hs[m*128 + c] = f2bf(hh);
        }
      }
    __syncthreads();
    #pragma unroll
    for (int i=0;i<8;++i){
      int id = tid + i*512, m = id>>4, c8 = id&15;
      int grow = Moff + m;
      if (grow < M){
        unsigned short* dst = (!sh) ? O1 + ((size_t)offe + grow)*256 + nc*128 + c8*8
                                    : O2 + (size_t)grow*512 + (size_t)(e-256)*256 + nc*128 + c8*8;
        *(f32x4*)dst = *(const f32x4*)(Hs + m*128 + c8*8);
      }
    }
  } else {
    if (sh){ // (y0+y1)/2 straight to d_out (f32)
      #pragma unroll
      for (int mi=0;mi<8;++mi)
        #pragma unroll
        for (int ni=0;ni<4;++ni)
          #pragma unroll
          for (int r=0;r<4;++r){
            int m = Moff + wm*128 + mi*16 + lk*4 + r;
            int c = nc*256 + wn*64 + ni*16 + lrow;
            OD[(size_t)m*1024 + c] = acc[mi][ni][r]*0.5f;
          }
    } else { // yslot bf16 via Hs, two column-half passes
      unsigned short* Hs = (unsigned short*)smem;
      #pragma unroll
      for (int pass=0; pass<2; ++pass){
        __syncthreads();
        if ((wn>>1) == pass){
          #pragma unroll
          for (int mi=0;mi<8;++mi)
            #pragma unroll
            for (int ni=0;ni<4;++ni)
              #pragma unroll
              for (int r=0;r<4;++r){
                int m = wm*128 + mi*16 + lk*4 + r;
                int c = (wn&1)*64 + ni*16 + lrow;
                Hs[m*128 + c] = f2bf(acc[mi][ni][r]);
              }
        }
        __syncthreads();
        #pragma unroll
        for (int i=0;i<8;++i){
          int id = tid + i*512, m = id>>4, c8 = id&15;
          int grow = Moff + m;
          if (grow < M){
            unsigned short* dst = O1 + ((size_t)offe+grow)*1024 + nc*256 + pass*128 + c8*8;
            *(f32x4*)dst = *(const f32x4*)(Hs + m*128 + c8*8);
          }
        }
      }
    }
  }
}

// ---------------- final gather: out = shared + sum_k w * yslot ----------------
__global__ void k_final(float* __restrict__ out, const unsigned short* __restrict__ yslot,
                        const int* __restrict__ slotmap, const float* __restrict__ topkw){
  __shared__ int sp[8]; __shared__ float sw[8];
  int t = blockIdx.x, tid = threadIdx.x;
  if (tid<8){ sp[tid]=slotmap[t*8+tid]; sw[tid]=topkw[t*8+tid]; }
  __syncthreads();
  int c = tid*4;
  f32x4 o = *(f32x4*)(out + (size_t)t*1024 + c);
  #pragma unroll
  for (int k=0;k<8;++k){
    u16x4 y = *(const u16x4*)(yslot + (size_t)sp[k]*1024 + c);
    float w = sw[k];
    o[0] += w*bf2f(y[0]); o[1] += w*bf2f(y[1]); o[2] += w*bf2f(y[2]); o[3] += w*bf2f(y[3]);
  }
  *(f32x4*)(out + (size_t)t*1024 + c) = o;
}

extern "C" void kernel_launch(void* const* d_in, const int* in_sizes, int n_in,
                              void* d_out, int out_size, void* d_ws, size_t ws_size,
                              hipStream_t stream) {
  const float* x    = (const float*)d_in[0];
  const float* Wg   = (const float*)d_in[1];
  const float* Wgu  = (const float*)d_in[2];
  const float* Wd   = (const float*)d_in[3];
  const float* Wsgu = (const float*)d_in[4];
  const float* Wsd  = (const float*)d_in[5];
  float* out = (float*)d_out;

  char* W = (char*)d_ws; // needs ~93 MB
  unsigned short* xbf    = (unsigned short*)(W + WS_XBF);
  unsigned short* hsh    = (unsigned short*)(W + WS_HSH);
  unsigned short* hmid   = (unsigned short*)(W + WS_HMID);
  unsigned short* yslot  = (unsigned short*)(W + WS_YSLOT);
  int*   topki   = (int*)(W + WS_TOPKI);
  float* topkw   = (float*)(W + WS_TOPKW);
  int*   tokmap  = (int*)(W + WS_TOKMAP);
  int*   slotmap = (int*)(W + WS_SLOTMAP);
  int*   cnt     = (int*)(W + WS_CNT);
  int*   cursor  = (int*)(W + WS_CURSOR);
  unsigned short* zpage = (unsigned short*)(W + WS_ZERO);
  int*   off     = (int*)(W + WS_OFF);

  // zero cnt|cursor|zeropage (contiguous 6144 B)
  hipMemsetAsync((void*)cnt, 0, 1024+1024+4096, stream);

  k_router <<<512, 256, 0, stream>>>(x, Wg, topki, topkw, cnt);
  k_convert<<<2048, 256, 0, stream>>>(x, xbf);
  k_scan   <<<1, 256, 0, stream>>>(cnt, off);
  k_scatter<<<128, 256, 0, stream>>>(topki, off, cursor, tokmap, slotmap);
  k_gemm<1><<<dim3(258,16,2), 512, 0, stream>>>(xbf, (const unsigned short*)nullptr,
        Wgu, Wsgu, cnt, off, tokmap, hmid, hsh, out, zpage);
  k_gemm<2><<<dim3(257,16,4), 512, 0, stream>>>(hmid, hsh,
        Wd, Wsd, cnt, off, tokmap, yslot, (unsigned short*)nullptr, out, zpage);
  k_final <<<4096, 256, 0, stream>>>(out, yslot, slotmap, topkw);
}

// Round 2
// 427.758 us; speedup vs baseline: 1.0582x; 1.0582x over previous
//
#include <hip/hip_runtime.h>
#include <hip/hip_bf16.h>

// DeepseekV3 MoE: B=2,S=2048 -> n=4096 tokens, H=1024, I=256, E=256, K=8, G=8, TG=4, NS=2
// All inputs f32. Output f32 [4096][1024].

typedef __attribute__((ext_vector_type(4))) float  f32x4;
typedef __attribute__((ext_vector_type(8))) short  bf16x8;
typedef __attribute__((ext_vector_type(4))) short  bf16x4;
typedef __attribute__((ext_vector_type(4))) unsigned short u16x4;

#define DI static __device__ __forceinline__

DI unsigned short f2bf(float f){
  unsigned u = __builtin_bit_cast(unsigned, f);
  return (unsigned short)((u + 0x7FFFu + ((u>>16)&1u)) >> 16); // RNE (inputs finite)
}
DI float bf2f(unsigned short s){
  return __builtin_bit_cast(float, ((unsigned)s)<<16);
}

// ---------------- workspace layout (bytes) ----------------
#define WS_XBF      0u          /* 4096*1024 bf16 = 8,388,608 */
#define WS_HSH      8388608u    /* 4096*512 bf16  = 4,194,304 (shared h, concat s) */
#define WS_HMID     12582912u   /* 32768*256 bf16 = 16,777,216 */
#define WS_YSLOT    29360128u   /* 32768*1024 bf16= 67,108,864 */
#define WS_TOPKI    96468992u   /* 4096*8 int */
#define WS_TOPKW    96600064u   /* 4096*8 f32 */
#define WS_TOKMAP   96731136u   /* 32768 int */
#define WS_SLOTMAP  96862208u   /* 32768 int */
#define WS_CNT      96993280u   /* 256 int */
#define WS_CURSOR   96994304u   /* 256 int */
#define WS_ZERO     96995328u   /* 4096 B zeros (covers k0*2 + lane offs) */
#define WS_OFF      96999424u   /* 257 int */

// ---------------- convert x -> bf16 ----------------
__global__ void k_convert(const float* __restrict__ x, unsigned short* __restrict__ xbf){
  size_t i = ((size_t)blockIdx.x*256 + threadIdx.x)*8;
  f32x4 v0 = *(const f32x4*)(x+i), v1 = *(const f32x4*)(x+i+4);
  u16x4 a, b;
  a[0]=f2bf(v0[0]); a[1]=f2bf(v0[1]); a[2]=f2bf(v0[2]); a[3]=f2bf(v0[3]);
  b[0]=f2bf(v1[0]); b[1]=f2bf(v1[1]); b[2]=f2bf(v1[2]); b[3]=f2bf(v1[3]);
  *(u16x4*)(xbf+i) = a; *(u16x4*)(xbf+i+4) = b;
}

// ---------------- router: logits (f32, f64-combined) + grouped top-k + softmax ----------------
__global__ __launch_bounds__(256) void k_router(const float* __restrict__ x, const float* __restrict__ Wg,
                                                int* __restrict__ topki, float* __restrict__ topkw,
                                                int* __restrict__ cnt){
  __shared__ float xs[8][1024];   // 32KB
  __shared__ float lg[8][256];    // 8KB
  __shared__ float cv[8][32];
  __shared__ int   ce[8][32];
  const int tid = threadIdx.x;
  const int t0  = blockIdx.x * 8;
  {
    const f32x4* xg = (const f32x4*)(x + (size_t)t0*1024);
    f32x4* xs4 = (f32x4*)&xs[0][0];
    #pragma unroll
    for (int i=0;i<8;++i) xs4[tid + i*256] = xg[tid + i*256];
  }
  __syncthreads();
  { // expert e = tid; 8 tokens; LDS reads are wave-uniform -> broadcast
    const f32x4* wg4 = (const f32x4*)(Wg + (size_t)tid*1024);
    f32x4 a[8];
    #pragma unroll
    for (int t=0;t<8;++t) a[t] = (f32x4){0.f,0.f,0.f,0.f};
    for (int i=0;i<256;++i){
      f32x4 w = wg4[i];
      #pragma unroll
      for (int t=0;t<8;++t) a[t] += w * ((const f32x4*)&xs[t][0])[i];
    }
    #pragma unroll
    for (int t=0;t<8;++t){
      double d = ((double)a[t][0] + (double)a[t][1]) + ((double)a[t][2] + (double)a[t][3]);
      lg[t][tid] = (float)d;
    }
  }
  __syncthreads();
  if (tid < 64){ // per (token, group): top-4 of 32, ties -> lowest index
    int tok = tid>>3, grp = tid&7;
    unsigned mask = 0;
    for (int j=0;j<4;++j){
      float best = -3.4e38f; int bi = 0;
      for (int i=0;i<32;++i){
        float v = lg[tok][grp*32+i];
        if (!((mask>>i)&1u) && v > best){ best=v; bi=i; }
      }
      mask |= 1u<<bi;
      cv[tok][grp*4+j] = best; ce[tok][grp*4+j] = grp*32+bi;
    }
  }
  __syncthreads();
  if (tid < 8){ // per token: top-8 of 32 candidates + softmax
    int tok = tid; unsigned mask=0;
    float vals[8]; int es[8];
    #pragma unroll
    for (int k=0;k<8;++k){
      float best=-3.4e38f; int bp=0;
      for (int p=0;p<32;++p){
        float v = cv[tok][p];
        if (!((mask>>p)&1u) && v > best){ best=v; bp=p; }
      }
      mask|=1u<<bp; vals[k]=best; es[k]=ce[tok][bp];
    }
    float m = vals[0], s=0.f, w[8];
    #pragma unroll
    for (int k=0;k<8;++k){ w[k]=expf(vals[k]-m); s+=w[k]; }
    float inv = 1.f/s;
    #pragma unroll
    for (int k=0;k<8;++k){
      int g=(t0+tok)*8+k;
      topki[g]=es[k]; topkw[g]=w[k]*inv;
      atomicAdd(&cnt[es[k]],1);
    }
  }
}

// ---------------- exclusive scan of 256 counts ----------------
__global__ void k_scan(const int* __restrict__ cnt, int* __restrict__ off){
  __shared__ int s[256];
  int tid=threadIdx.x;
  s[tid]=cnt[tid]; __syncthreads();
  for (int d=1; d<256; d<<=1){
    int v = (tid>=d)? s[tid-d] : 0; __syncthreads();
    s[tid]+=v; __syncthreads();
  }
  off[tid+1]=s[tid]; if(tid==0) off[0]=0;
}

// ---------------- scatter tokens into per-expert slots ----------------
__global__ void k_scatter(const int* __restrict__ topki, const int* __restrict__ off,
                          int* __restrict__ cursor, int* __restrict__ tokmap, int* __restrict__ slotmap){
  int g = blockIdx.x*256 + threadIdx.x;
  int e = topki[g];
  int p = off[e] + atomicAdd(&cursor[e], 1);
  tokmap[p] = g >> 3;
  slotmap[g] = p;
}

// ---------------- ragged MFMA GEMM (BM=256, BN=256, BK=32, 8 waves) ----------------
// Fully DMA-staged (global_load_lds for A bf16 and B f32), double-buffered,
// counted vmcnt(6) + raw barriers so next tile's loads stay in flight across
// the barrier (T3/T4). B kept f32 in LDS with lane-XOR source pre-swizzle
// (reader lands at 2-way conflict = free); converted to bf16 at read.
template<int GEMM>
__global__ __launch_bounds__(512, 2) void k_gemm(
    const unsigned short* __restrict__ A1, const unsigned short* __restrict__ A2,
    const float* __restrict__ WE, const float* __restrict__ WS,
    const int* __restrict__ cnt, const int* __restrict__ off,
    const int* __restrict__ tokmap,
    unsigned short* __restrict__ O1, unsigned short* __restrict__ O2,
    float* __restrict__ OD, const unsigned short* __restrict__ zpage)
{
  __shared__ __align__(16) char smem[98304]; // As[2][256][32]bf16 (32KB) | Bs[2][32][256]f32 (64KB); epilogue reuses as Hs
  const int e = blockIdx.x, mt = blockIdx.y, nc = blockIdx.z;
  const bool sh = (e >= 256);
  const int M = sh ? 4096 : cnt[e];
  const int Moff = mt*256;
  if (Moff >= M) return;
  const int tid=threadIdx.x, ln=tid&63, wv=tid>>6, wm=wv>>2, wn=wv&3, lrow=ln&15, lk=ln>>4;
  const int Ktot = (GEMM==1)?1024:(sh?512:256);
  const int ldB  = (GEMM==1)?512:1024;
  const float* Bp = (GEMM==1) ? (sh? WS + (size_t)(e-256)*524288 : WE + (size_t)e*524288)
                              : (sh? WS : WE + (size_t)e*262144);
  const int offe = sh? 0 : off[e];

  // per-thread A staging sources (2 gload_lds per wave per K-step, 16B/lane)
  const char* a_src[2];
  #pragma unroll
  for (int qi=0;qi<2;++qi){
    int row  = (wv*2+qi)*16 + (ln>>2);
    int grow = Moff + row;
    const unsigned short* p;
    if (GEMM==1){
      if (!sh) p = (grow < M)? A1 + (size_t)tokmap[offe+grow]*1024 : zpage;
      else     p = A1 + (size_t)grow*1024;
    } else {
      if (!sh) p = (grow < M)? A1 + ((size_t)offe+grow)*256 : zpage;
      else     p = A2 + (size_t)grow*512;
    }
    a_src[qi] = (const char*)p + (ln&3)*16;
  }
  // per-thread B staging sources (4 gload_lds per wave per K-step, 16B/lane),
  // global col-group pre-swizzled by wave's k-octet so reads are conflict-free
  const char* b_src[4];
  {
    int swz = ((wv>>1)&3)<<2;          // (kr>>3)<<2, kr = wv*4+r -> depends only on wv
    int cg  = ln ^ swz;                // col group (16B) this lane fetches
    int tcb = cg*4;                    // tile col base
    int gcol = (GEMM==1)? (nc*128 + tcb + ((tcb>=128)?128:0)) : (nc*256 + tcb);
    #pragma unroll
    for (int r=0;r<4;++r){
      int kr = wv*4 + r;
      b_src[r] = (const char*)(Bp + (size_t)kr*ldB + gcol);
    }
  }

  f32x4 acc[8][4] = {};

  auto stage = [&](int buf, int k0){
    #pragma unroll
    for (int qi=0;qi<2;++qi)
      __builtin_amdgcn_global_load_lds((const void*)(a_src[qi] + (size_t)k0*2),
          (void*)(smem + buf*16384 + (wv*2+qi)*1024), 16, 0, 0);
    #pragma unroll
    for (int r=0;r<4;++r)
      __builtin_amdgcn_global_load_lds((const void*)(b_src[r] + (size_t)k0*ldB*4),
          (void*)(smem + 32768 + buf*32768 + (wv*4+r)*1024), 16, 0, 0);
  };

  auto compute = [&](int buf){
    const short* as  = (const short*)(smem + buf*16384);
    const float* bs  = (const float*)(smem + 32768 + buf*32768);
    bf16x8 af[8];
    #pragma unroll
    for (int mi=0;mi<8;++mi) af[mi] = *(const bf16x8*)(as + (wm*128+mi*16+lrow)*32 + lk*8);
    #pragma unroll
    for (int ni=0;ni<4;++ni){
      int n0 = (GEMM==1)? ((ni<2)? wn*32+ni*16 : 128+wn*32+(ni-2)*16) : (wn*64+ni*16);
      int tc = n0 + lrow;
      int sloff = ((((tc>>2) ^ (lk<<2))<<2) | (tc&3));   // swizzled float index within row
      const float* colp = bs + (size_t)lk*8*256 + sloff;
      bf16x8 bv;
      #pragma unroll
      for (int j=0;j<8;++j){
        unsigned u = __builtin_bit_cast(unsigned, colp[(size_t)j*256]);
        bv[j] = (short)((u + 0x8000u) >> 16);            // round-half-up to bf16
      }
      #pragma unroll
      for (int mi=0;mi<8;++mi)
        acc[mi][ni] = __builtin_amdgcn_mfma_f32_16x16x32_bf16(af[mi], bv, acc[mi][ni], 0,0,0);
    }
  };

  stage(0, 0);
  const int ns = Ktot>>5;
  for (int t=0;t<ns;++t){
    int b = t&1;
    if (t+1<ns){
      stage(b^1, (t+1)<<5);                               // next tile's 6 loads issued FIRST
      asm volatile("s_waitcnt vmcnt(6)" ::: "memory");    // retire this tile's 6, keep next in flight
    } else {
      asm volatile("s_waitcnt vmcnt(0)" ::: "memory");
    }
    asm volatile("s_barrier" ::: "memory");               // all waves' DMA for buf b landed
    compute(b);
    asm volatile("s_barrier" ::: "memory");               // buf b free for next DMA
  }

  if (GEMM==1){ // silu(g)*u epilogue via LDS repack (Hs aliases smem)
    __syncthreads();
    unsigned short* Hs = (unsigned short*)smem; // [256][128]
    #pragma unroll
    for (int mi=0;mi<8;++mi)
      #pragma unroll
      for (int ni=0;ni<2;++ni){
        f32x4 g = acc[mi][ni], u = acc[mi][ni+2];
        #pragma unroll
        for (int r=0;r<4;++r){
          float gg = g[r];
          float hh = (gg / (1.f + __expf(-gg))) * u[r];
          int m = wm*128 + mi*16 + lk*4 + r;
          int c = wn*32 + ni*16 + lrow;
          Hs[m*128 + c] = f2bf(hh);
        }
      }
    __syncthreads();
    #pragma unroll
    for (int i=0;i<8;++i){
      int id = tid + i*512, m = id>>4, c8 = id&15;
      int grow = Moff + m;
      if (grow < M){
        unsigned short* dst = (!sh) ? O1 + ((size_t)offe + grow)*256 + nc*128 + c8*8
                                    : O2 + (size_t)grow*512 + (size_t)(e-256)*256 + nc*128 + c8*8;
        *(f32x4*)dst = *(const f32x4*)(Hs + m*128 + c8*8);
      }
    }
  } else {
    if (sh){ // (y0+y1)/2 straight to d_out (f32)
      #pragma unroll
      for (int mi=0;mi<8;++mi)
        #pragma unroll
        for (int ni=0;ni<4;++ni)
          #pragma unroll
          for (int r=0;r<4;++r){
            int m = Moff + wm*128 + mi*16 + lk*4 + r;
            int c = nc*256 + wn*64 + ni*16 + lrow;
            OD[(size_t)m*1024 + c] = acc[mi][ni][r]*0.5f;
          }
    } else { // yslot bf16 via Hs, two column-half passes
      unsigned short* Hs = (unsigned short*)smem;
      #pragma unroll
      for (int pass=0; pass<2; ++pass){
        __syncthreads();
        if ((wn>>1) == pass){
          #pragma unroll
          for (int mi=0;mi<8;++mi)
            #pragma unroll
            for (int ni=0;ni<4;++ni)
              #pragma unroll
              for (int r=0;r<4;++r){
                int m = wm*128 + mi*16 + lk*4 + r;
                int c = (wn&1)*64 + ni*16 + lrow;
                Hs[m*128 + c] = f2bf(acc[mi][ni][r]);
              }
        }
        __syncthreads();
        #pragma unroll
        for (int i=0;i<8;++i){
          int id = tid + i*512, m = id>>4, c8 = id&15;
          int grow = Moff + m;
          if (grow < M){
            unsigned short* dst = O1 + ((size_t)offe+grow)*1024 + nc*256 + pass*128 + c8*8;
            *(f32x4*)dst = *(const f32x4*)(Hs + m*128 + c8*8);
          }
        }
      }
    }
  }
}

// ---------------- final gather: out = shared + sum_k w * yslot ----------------
__global__ void k_final(float* __restrict__ out, const unsigned short* __restrict__ yslot,
                        const int* __restrict__ slotmap, const float* __restrict__ topkw){
  __shared__ int sp[8]; __shared__ float sw[8];
  int t = blockIdx.x, tid = threadIdx.x;
  if (tid<8){ sp[tid]=slotmap[t*8+tid]; sw[tid]=topkw[t*8+tid]; }
  __syncthreads();
  int c = tid*4;
  f32x4 o = *(f32x4*)(out + (size_t)t*1024 + c);
  #pragma unroll
  for (int k=0;k<8;++k){
    u16x4 y = *(const u16x4*)(yslot + (size_t)sp[k]*1024 + c);
    float w = sw[k];
    o[0] += w*bf2f(y[0]); o[1] += w*bf2f(y[1]); o[2] += w*bf2f(y[2]); o[3] += w*bf2f(y[3]);
  }
  *(f32x4*)(out + (size_t)t*1024 + c) = o;
}

extern "C" void kernel_launch(void* const* d_in, const int* in_sizes, int n_in,
                              void* d_out, int out_size, void* d_ws, size_t ws_size,
                              hipStream_t stream) {
  const float* x    = (const float*)d_in[0];
  const float* Wg   = (const float*)d_in[1];
  const float* Wgu  = (const float*)d_in[2];
  const float* Wd   = (const float*)d_in[3];
  const float* Wsgu = (const float*)d_in[4];
  const float* Wsd  = (const float*)d_in[5];
  float* out = (float*)d_out;

  char* W = (char*)d_ws; // needs ~93 MB
  unsigned short* xbf    = (unsigned short*)(W + WS_XBF);
  unsigned short* hsh    = (unsigned short*)(W + WS_HSH);
  unsigned short* hmid   = (unsigned short*)(W + WS_HMID);
  unsigned short* yslot  = (unsigned short*)(W + WS_YSLOT);
  int*   topki   = (int*)(W + WS_TOPKI);
  float* topkw   = (float*)(W + WS_TOPKW);
  int*   tokmap  = (int*)(W + WS_TOKMAP);
  int*   slotmap = (int*)(W + WS_SLOTMAP);
  int*   cnt     = (int*)(W + WS_CNT);
  int*   cursor  = (int*)(W + WS_CURSOR);
  unsigned short* zpage = (unsigned short*)(W + WS_ZERO);
  int*   off     = (int*)(W + WS_OFF);

  // zero cnt|cursor|zeropage (contiguous 6144 B)
  hipMemsetAsync((void*)cnt, 0, 1024+1024+4096, stream);

  k_router <<<512, 256, 0, stream>>>(x, Wg, topki, topkw, cnt);
  k_convert<<<2048, 256, 0, stream>>>(x, xbf);
  k_scan   <<<1, 256, 0, stream>>>(cnt, off);
  k_scatter<<<128, 256, 0, stream>>>(topki, off, cursor, tokmap, slotmap);
  k_gemm<1><<<dim3(258,16,2), 512, 0, stream>>>(xbf, (const unsigned short*)nullptr,
        Wgu, Wsgu, cnt, off, tokmap, hmid, hsh, out, zpage);
  k_gemm<2><<<dim3(257,16,4), 512, 0, stream>>>(hmid, hsh,
        Wd, Wsd, cnt, off, tokmap, yslot, (unsigned short*)nullptr, out, zpage);
  k_final <<<4096, 256, 0, stream>>>(out, yslot, slotmap, topkw);
}